// Round 3
// 172.223 us; speedup vs baseline: 1.0076x; 1.0076x over previous
//
#include <hip/hip_runtime.h>
#include <stdint.h>

#define IMG 224
#define OUT_DIM 112
#define NCH 16
#define TILE 32        // conv tile (x and y) per block
#define P_ROWS 36      // TILE + 4 halo rows
#define P_COLS 36      // real pair cols; [36..47] zero-filled pad (read by g=3 spare slots)
#define P_STRIDE 48    // dwords; 48 ≡ 16 (mod 32): row-groups tile LDS banks 2-way (free)

typedef _Float16 h8t  __attribute__((ext_vector_type(8)));
typedef float    f32x4 __attribute__((ext_vector_type(4)));
typedef uint32_t u32x4 __attribute__((ext_vector_type(4)));

// d_ws layout (uint32 words):
//   [0 .. 31]    : 16 x float2 (scale, shift) per channel (folds conv_b, mean, beta)
//   [32 .. 287]  : Bfrag: 64 lanes x 4 dwords = mfma_f32_16x16x32_f16 B operand.
//                  lane (ch = l&15, g = l>>4), k = 8*g + j:
//                    j=0..4 -> (dy=g, dx=j) ; j=5 -> 0
//                    j=6,7  -> (dy=4, dx=2g, 2g+1) for 2g<5, else 0
//                  => ONE K=32 MFMA covers the full 5x5 kernel. No legacy shapes.
#define WS_B1 32

__global__ void prep_kernel(const float* __restrict__ conv_w,
                            const float* __restrict__ conv_b,
                            const float* __restrict__ gamma,
                            const float* __restrict__ beta,
                            const float* __restrict__ run_mean,
                            const float* __restrict__ run_var,
                            uint32_t* __restrict__ ws)
{
    int l = threadIdx.x;
    if (l >= 64) return;
    if (l < NCH) {
        float s = gamma[l] * rsqrtf(run_var[l] + 1e-5f);
        float t = fmaf(s, conv_b[l] - run_mean[l], beta[l]);
        ((float2*)ws)[l] = make_float2(s, t);
    }
    const int ch = l & 15;
    const int g  = l >> 4;
    const float* w = conv_w + ch * 25;

    float w0 = w[g * 5 + 0], w1 = w[g * 5 + 1], w2 = w[g * 5 + 2];
    float w3 = w[g * 5 + 3], w4 = w[g * 5 + 4];
    const float* wr4 = w + 20;   // dy = 4 kernel row
    float e0 = (2 * g + 0 < 5) ? wr4[2 * g + 0] : 0.f;
    float e1 = (2 * g + 1 < 5) ? wr4[2 * g + 1] : 0.f;

    auto p0 = __builtin_amdgcn_cvt_pkrtz(w0, w1);
    auto p1 = __builtin_amdgcn_cvt_pkrtz(w2, w3);
    auto p2 = __builtin_amdgcn_cvt_pkrtz(w4, 0.f);
    auto p3 = __builtin_amdgcn_cvt_pkrtz(e0, e1);
    ws[WS_B1 + l * 4 + 0] = __builtin_bit_cast(uint32_t, p0);
    ws[WS_B1 + l * 4 + 1] = __builtin_bit_cast(uint32_t, p1);
    ws[WS_B1 + l * 4 + 2] = __builtin_bit_cast(uint32_t, p2);
    ws[WS_B1 + l * 4 + 3] = __builtin_bit_cast(uint32_t, p3);
}

// Implicit-GEMM conv: M=16 pixels, N=16 channels, K=32 (25 taps + zero pad),
// a single mfma_f32_16x16x32_f16 per conv row per 16-pixel subtile.
// A-frag: lane (pp = l&15, g = l>>4) supplies A[row=pp][k=8g+j]:
//   dwords 0..2: pairs (dx0,1)(dx2,3)(dx4,j5-junk*0) of row (Y + g)   [dy = g]
//   dword  3   : pair  (dx 2g, 2g+1) of row (Y + 4)                   [dy = 4]
// All junk slots are multiplied by exact-zero weights and all staged data is
// finite (pad cols zero-filled) -> no NaN.
// D-frag: col = l&15 = channel, row = 4*(l>>4)+reg = pixel -> 4 consecutive x per
// lane: 2x2 maxpool is in-lane (horizontal) + across the two row accumulators.
__global__ __launch_bounds__(256)
void conv_bn_relu_pool(const float* __restrict__ x,
                       const uint32_t* __restrict__ ws,
                       float* __restrict__ out)
{
    __shared__ uint32_t P[P_ROWS * P_STRIDE];

    const int tid = threadIdx.x;
    const int b  = blockIdx.z;
    const int ty = blockIdx.y * TILE;
    const int tx = blockIdx.x * TILE;
    const float* xb = x + (size_t)b * IMG * IMG;

    // Stage sliding half2 pairs from global (zero-padded halo + zero pad cols).
    // P row r = input row (ty-2+r); P col c = pair (in[tx-2+c], in[tx-2+c+1]).
    for (int i = tid; i < P_ROWS * P_STRIDE; i += 256) {
        int r = i / P_STRIDE, c = i - r * P_STRIDE;
        float v0 = 0.f, v1 = 0.f;
        int gy = ty - 2 + r;
        int gx = tx - 2 + c;
        if (c < P_COLS && (unsigned)gy < IMG) {
            const float* row = xb + gy * IMG;
            if ((unsigned)gx < IMG) v0 = row[gx];
            if ((unsigned)(gx + 1) < IMG) v1 = row[gx + 1];
        }
        auto p = __builtin_amdgcn_cvt_pkrtz(v0, v1);
        P[i] = __builtin_bit_cast(uint32_t, p);
    }

    const int lane = tid & 63;
    const int wv   = tid >> 6;
    const int pp   = lane & 15;   // A-frag pixel row == D-frag channel column
    const int g    = lane >> 4;   // k-group == D-frag pixel group

    // Weight fragment: wave-invariant per lane, loaded once (coalesced 16B).
    u32x4 b1u = *(const u32x4*)(ws + WS_B1 + lane * 4);
    h8t  B1 = __builtin_bit_cast(h8t, b1u);
    float2 sst = ((const float2*)ws)[pp];  // (scale, shift) for this lane's channel

    __syncthreads();

    float* outb = out + ((size_t)b * NCH + pp) * (OUT_DIM * OUT_DIM);

    // Each wave: 4 pooled rows x (2 subtiles of 16 conv x). 2 MFMAs per subtile.
    for (int s = 0; s < 4; ++s) {
        const int yl = 8 * wv + 2 * s;           // conv rows yl, yl+1
        const int oy = (ty >> 1) + 4 * wv + s;   // global pooled row
        #pragma unroll
        for (int sub = 0; sub < 2; ++sub) {
            const int cb = sub * 16 + pp;
            const uint32_t* rA = P + (yl + g) * P_STRIDE + cb;       // dy = g rows
            const uint32_t* r4 = P + (yl + 4) * P_STRIDE + cb + 2*g; // dy = 4 pair

            f32x4 accA = {0.f, 0.f, 0.f, 0.f};
            f32x4 accB = {0.f, 0.f, 0.f, 0.f};

            // conv row yl
            u32x4 a1 = {rA[0], rA[2], rA[4], r4[0]};
            accA = __builtin_amdgcn_mfma_f32_16x16x32_f16(
                       __builtin_bit_cast(h8t, a1), B1, accA, 0, 0, 0);
            // conv row yl+1
            u32x4 c1 = {rA[P_STRIDE], rA[P_STRIDE + 2], rA[P_STRIDE + 4], r4[P_STRIDE]};
            accB = __builtin_amdgcn_mfma_f32_16x16x32_f16(
                       __builtin_bit_cast(h8t, c1), B1, accB, 0, 0, 0);

            // maxpool (commutes with monotone BN scale>0 + ReLU) then epilogue
            float m0 = fmaxf(fmaxf(accA[0], accA[1]), fmaxf(accB[0], accB[1]));
            float m1 = fmaxf(fmaxf(accA[2], accA[3]), fmaxf(accB[2], accB[3]));
            float y0 = fmaxf(fmaf(m0, sst.x, sst.y), 0.f);
            float y1 = fmaxf(fmaf(m1, sst.x, sst.y), 0.f);

            const int ox = (tx >> 1) + sub * 8 + 2 * g;
            *(float2*)(outb + oy * OUT_DIM + ox) = make_float2(y0, y1);
        }
    }
}

extern "C" void kernel_launch(void* const* d_in, const int* in_sizes, int n_in,
                              void* d_out, int out_size, void* d_ws, size_t ws_size,
                              hipStream_t stream) {
    const float* x        = (const float*)d_in[0];
    const float* conv_w   = (const float*)d_in[1];
    const float* conv_b   = (const float*)d_in[2];
    const float* gamma    = (const float*)d_in[3];
    const float* beta     = (const float*)d_in[4];
    const float* run_mean = (const float*)d_in[5];
    const float* run_var  = (const float*)d_in[6];
    float* out = (float*)d_out;
    uint32_t* ws = (uint32_t*)d_ws;

    prep_kernel<<<1, 64, 0, stream>>>(conv_w, conv_b, gamma, beta, run_mean, run_var, ws);

    dim3 grid(IMG / TILE, IMG / TILE, 128);   // 7 x 7 x 128
    dim3 block(256);
    conv_bn_relu_pool<<<grid, block, 0, stream>>>(x, ws, out);
}

// Round 4
// 153.266 us; speedup vs baseline: 1.1322x; 1.1237x over previous
//
#include <hip/hip_runtime.h>
#include <stdint.h>

#define IMG 224
#define OUT_DIM 112
#define NCH 16
#define TILE_Y 16          // conv rows per block (full 224-wide strip)
#define R_ROWS 20          // TILE_Y + 4 halo rows
#define HJ 116             // padded pair-cols per parity plane (max read index 114)
#define HSZ (R_ROWS * HJ)  // 2320 dwords per parity plane

typedef _Float16 h8t  __attribute__((ext_vector_type(8)));
typedef float    f32x4 __attribute__((ext_vector_type(4)));
typedef uint32_t u32x4 __attribute__((ext_vector_type(4)));

// Implicit-GEMM conv (M=16 pixels, N=16 ch, K=32 = 25 taps + zero pad), one
// mfma_f32_16x16x32_f16 per conv row per 16-pixel subtile. Same verified
// fragment mapping as the previous passing kernel:
//   B lane (ch=l&15, g=l>>4): k=8g+j -> (dy=g, dx=j) j<5; j=6,7 -> (dy=4, dx=2g,2g+1)
//   A lane (pp=l&15, g=l>>4): dwords = pairs (dx0,1)(dx2,3)(dx4,.) of row y+g
//                             + pair (dx 2g,2g+1) of row y+4
//   D lane (pp, g) reg r: pixel 4g+r, channel pp -> 2x2 pool in-lane + across rows.
// LDS: parity-split sliding pairs. e[i] = in[i-2] (zero-padded);
//   H0[r][j] = (e[2j], e[2j+1]), H1[r][j] = (e[2j+1], e[2j+2]).
// Pair C lives at H[C&1][C>>1]; a lane's three A-dwords (pairs C, C+2, C+4)
// are contiguous in its parity plane -> ds_read2_b32 friendly.
__global__ __launch_bounds__(256)
void conv_bn_relu_pool(const float* __restrict__ x,
                       const float* __restrict__ conv_w,
                       const float* __restrict__ conv_b,
                       const float* __restrict__ gamma,
                       const float* __restrict__ beta,
                       const float* __restrict__ run_mean,
                       const float* __restrict__ run_var,
                       float* __restrict__ out)
{
    __shared__ uint32_t H[2 * HSZ];

    const int tid = threadIdx.x;
    const int b   = blockIdx.y;
    const int ty  = blockIdx.x * TILE_Y;
    const float* xb = x + (size_t)b * IMG * IMG;

    const int lane = tid & 63;
    const int wv   = tid >> 6;
    const int pp   = lane & 15;   // A-row pixel index == D channel column
    const int g    = lane >> 4;   // k-group == D pixel group

    // ---- B fragment + BN constants in-register (replaces prep kernel) ----
    const float* w = conv_w + pp * 25;
    float w0 = w[g*5+0], w1 = w[g*5+1], w2 = w[g*5+2], w3 = w[g*5+3], w4 = w[g*5+4];
    float e0 = (2*g   < 5) ? w[20 + 2*g]     : 0.f;
    float e1 = (2*g+1 < 5) ? w[20 + 2*g + 1] : 0.f;
    u32x4 bu;
    bu[0] = __builtin_bit_cast(uint32_t, __builtin_amdgcn_cvt_pkrtz(w0, w1));
    bu[1] = __builtin_bit_cast(uint32_t, __builtin_amdgcn_cvt_pkrtz(w2, w3));
    bu[2] = __builtin_bit_cast(uint32_t, __builtin_amdgcn_cvt_pkrtz(w4, 0.f));
    bu[3] = __builtin_bit_cast(uint32_t, __builtin_amdgcn_cvt_pkrtz(e0, e1));
    h8t B1 = __builtin_bit_cast(h8t, bu);
    float sc = gamma[pp] * rsqrtf(run_var[pp] + 1e-5f);
    float sh = fmaf(sc, conv_b[pp] - run_mean[pp], beta[pp]);

    // ---- stage full-width strip: both parity planes from 3 loads per 2 pairs ----
    for (int i = tid; i < HSZ; i += 256) {
        int r = i / HJ, j = i - r * HJ;
        int gy = ty - 2 + r;
        int c  = 2 * j;          // e-base; e[c] = in[c-2]
        float v0 = 0.f, v1 = 0.f, v2 = 0.f;
        if ((unsigned)gy < IMG) {
            const float* row = xb + gy * IMG;
            if ((unsigned)(c - 2) < IMG) v0 = row[c - 2];
            if ((unsigned)(c - 1) < IMG) v1 = row[c - 1];
            if ((unsigned)(c    ) < IMG) v2 = row[c];
        }
        H[i]       = __builtin_bit_cast(uint32_t, __builtin_amdgcn_cvt_pkrtz(v0, v1));
        H[HSZ + i] = __builtin_bit_cast(uint32_t, __builtin_amdgcn_cvt_pkrtz(v1, v2));
    }
    __syncthreads();

    const uint32_t* Hq = H + (pp & 1) * HSZ + (pp >> 1);
    float* outb = out + ((size_t)b * NCH + pp) * (OUT_DIM * OUT_DIM);

    // Each wave: 2 pooled rows x full 112-wide (14 subtiles x 2 MFMAs each).
    #pragma unroll
    for (int s = 0; s < 2; ++s) {
        const int y0 = 4 * wv + 2 * s;                  // conv rows y0, y0+1
        const int oy = blockIdx.x * 8 + 2 * wv + s;     // global pooled row
        const uint32_t* rA = Hq + (y0 + g) * HJ;        // dy = g rows
        const uint32_t* r4 = Hq + (y0 + 4) * HJ + g;    // dy = 4 row
        float* orow = outb + oy * OUT_DIM + 2 * g;

        #pragma unroll
        for (int sub = 0; sub < 14; ++sub) {
            const int j0 = sub * 8;
            f32x4 accA = {0.f, 0.f, 0.f, 0.f};
            f32x4 accB = {0.f, 0.f, 0.f, 0.f};

            u32x4 a1 = { rA[j0], rA[j0 + 1], rA[j0 + 2], r4[j0] };
            accA = __builtin_amdgcn_mfma_f32_16x16x32_f16(
                       __builtin_bit_cast(h8t, a1), B1, accA, 0, 0, 0);
            u32x4 c1 = { rA[j0 + HJ], rA[j0 + 1 + HJ], rA[j0 + 2 + HJ], r4[j0 + HJ] };
            accB = __builtin_amdgcn_mfma_f32_16x16x32_f16(
                       __builtin_bit_cast(h8t, c1), B1, accB, 0, 0, 0);

            // maxpool (commutes with monotone BN scale>0 + ReLU) then epilogue
            float m0 = fmaxf(fmaxf(accA[0], accA[1]), fmaxf(accB[0], accB[1]));
            float m1 = fmaxf(fmaxf(accA[2], accA[3]), fmaxf(accB[2], accB[3]));
            float y0v = fmaxf(fmaf(m0, sc, sh), 0.f);
            float y1v = fmaxf(fmaf(m1, sc, sh), 0.f);
            *(float2*)(orow + sub * 8) = make_float2(y0v, y1v);
        }
    }
}

extern "C" void kernel_launch(void* const* d_in, const int* in_sizes, int n_in,
                              void* d_out, int out_size, void* d_ws, size_t ws_size,
                              hipStream_t stream) {
    const float* x        = (const float*)d_in[0];
    const float* conv_w   = (const float*)d_in[1];
    const float* conv_b   = (const float*)d_in[2];
    const float* gamma    = (const float*)d_in[3];
    const float* beta     = (const float*)d_in[4];
    const float* run_mean = (const float*)d_in[5];
    const float* run_var  = (const float*)d_in[6];
    float* out = (float*)d_out;

    dim3 grid(IMG / TILE_Y, 128);   // 14 strips x 128 batch
    dim3 block(256);
    conv_bn_relu_pool<<<grid, block, 0, stream>>>(
        x, conv_w, conv_b, gamma, beta, run_mean, run_var, out);
}

// Round 6
// 148.144 us; speedup vs baseline: 1.1714x; 1.0346x over previous
//
#include <hip/hip_runtime.h>
#include <stdint.h>

#define IMG 224
#define OUT_DIM 112
#define NCH 16
#define TILE_Y 32          // conv rows per block (full 224-wide strip)
#define R_ROWS 36          // TILE_Y + 4 halo rows
#define HJ 116             // dwords per plane row: 2 front pad + 112 pairs + 2 tail pad
#define HSZ (R_ROWS * HJ)  // dwords per parity plane

typedef _Float16 h8t  __attribute__((ext_vector_type(8)));
typedef float    f32x4 __attribute__((ext_vector_type(4)));
typedef uint32_t u32x4 __attribute__((ext_vector_type(4)));

// Implicit-GEMM conv (M=16 pixels, N=16 ch, K=32 = 25 taps + zero pad), one
// mfma_f32_16x16x32_f16 per conv row per 16-pixel subtile. Verified mapping:
//   B lane (ch=l&15, g=l>>4): k=8g+j -> (dy=g, dx=j) j<5; j=6,7 -> (dy=4, dx=2g,2g+1)
//   A lane (pp=l&15, g=l>>4): pairs (dx0,1)(dx2,3)(dx4,junk*0) of row y+g
//                             + pair (dx 2g,2g+1) of row y+4
//   D lane (pp,g) reg r: pixel 4g+r, channel pp -> 2x2 pool in-lane + across rows.
// LDS: parity-split pair planes, pair C = (in[C], in[C+1]) at plane[C&1],
//   row dword 2 + floor(C/2). Front pads: plane0 dword1 = pair C=-2 = (0,0);
//   plane1 dword1 = pair C=-1 = (0, in[0])  <- REAL DATA, was the R5 bug.
//   Tail dwords 114/115 = pairs C>=224, genuinely all-zero.
//   Lane's three A-dwords are contiguous in its plane -> ds_read2_b32 friendly.
//   Staging: one float4 + one scalar per thread -> 2 aligned ds_write_b64.
__global__ __launch_bounds__(256)
void conv_bn_relu_pool(const float* __restrict__ x,
                       const float* __restrict__ conv_w,
                       const float* __restrict__ conv_b,
                       const float* __restrict__ gamma,
                       const float* __restrict__ beta,
                       const float* __restrict__ run_mean,
                       const float* __restrict__ run_var,
                       float* __restrict__ out)
{
    __shared__ __align__(16) uint32_t H[2 * HSZ];

    const int tid = threadIdx.x;
    const int b   = blockIdx.y;
    const int ty  = blockIdx.x * TILE_Y;
    const float* xb = x + (size_t)b * IMG * IMG;

    const int lane = tid & 63;
    const int wv   = tid >> 6;
    const int pp   = lane & 15;   // A-row pixel index == D channel column
    const int g    = lane >> 4;   // k-group == D pixel group

    // ---- B fragment + BN constants in-register ----
    const float* w = conv_w + pp * 25;
    float w0 = w[g*5+0], w1 = w[g*5+1], w2 = w[g*5+2], w3 = w[g*5+3], w4 = w[g*5+4];
    float e0 = (2*g   < 5) ? w[20 + 2*g]     : 0.f;
    float e1 = (2*g+1 < 5) ? w[20 + 2*g + 1] : 0.f;
    u32x4 bu;
    bu[0] = __builtin_bit_cast(uint32_t, __builtin_amdgcn_cvt_pkrtz(w0, w1));
    bu[1] = __builtin_bit_cast(uint32_t, __builtin_amdgcn_cvt_pkrtz(w2, w3));
    bu[2] = __builtin_bit_cast(uint32_t, __builtin_amdgcn_cvt_pkrtz(w4, 0.f));
    bu[3] = __builtin_bit_cast(uint32_t, __builtin_amdgcn_cvt_pkrtz(e0, e1));
    h8t B1 = __builtin_bit_cast(h8t, bu);
    float sc = gamma[pp] * rsqrtf(run_var[pp] + 1e-5f);
    float sh = fmaf(sc, conv_b[pp] - run_mean[pp], beta[pp]);

    // ---- stage strip: float4-coalesced, both parity planes, aligned b64 writes ----
    for (int i = tid; i < R_ROWS * 56; i += 256) {
        int r = i / 56, q = i - r * 56;
        int gy = ty - 2 + r;
        int c  = 4 * q;
        f32x4 v = {0.f, 0.f, 0.f, 0.f};
        float v4 = 0.f;
        if ((unsigned)gy < IMG) {
            const float* row = xb + gy * IMG;
            v = *(const f32x4*)(row + c);
            if (q < 55) v4 = row[c + 4];
        }
        uint32_t* base = H + r * HJ + 2 + (c >> 1);
        uint2 p0, p1;
        p0.x = __builtin_bit_cast(uint32_t, __builtin_amdgcn_cvt_pkrtz(v[0], v[1]));
        p0.y = __builtin_bit_cast(uint32_t, __builtin_amdgcn_cvt_pkrtz(v[2], v[3]));
        p1.x = __builtin_bit_cast(uint32_t, __builtin_amdgcn_cvt_pkrtz(v[1], v[2]));
        p1.y = __builtin_bit_cast(uint32_t, __builtin_amdgcn_cvt_pkrtz(v[3], v4));
        *(uint2*)(base)       = p0;
        *(uint2*)(base + HSZ) = p1;
    }
    // pad dwords {0,1} and {114,115} of every plane row (disjoint from staging).
    // plane1 dword1 = pair C=-1 = (0, in[row][0]) -- carries real data.
    if (tid < 2 * R_ROWS) {
        int pl = tid & 1, r = tid >> 1;
        int gy = ty - 2 + r;
        float f0 = 0.f;
        if (pl == 1 && (unsigned)gy < IMG) f0 = xb[gy * IMG];
        uint32_t pm1 = __builtin_bit_cast(uint32_t, __builtin_amdgcn_cvt_pkrtz(0.f, f0));
        uint32_t* row = H + pl * HSZ + r * HJ;
        row[0] = 0u;
        row[1] = pl ? pm1 : 0u;
        *(uint2*)(row + 114) = make_uint2(0u, 0u);
    }
    __syncthreads();

    const uint32_t* Hq = H + (pp & 1) * HSZ + (pp >> 1) + 1;
    float* outb = out + ((size_t)b * NCH + pp) * (OUT_DIM * OUT_DIM);

    // Each wave: 4 pooled rows x full 112-wide (14 subtiles x 2 MFMAs each).
    #pragma unroll
    for (int s = 0; s < 4; ++s) {
        const int y0 = 8 * wv + 2 * s;                   // conv rows y0, y0+1
        const int oy = blockIdx.x * 16 + 4 * wv + s;     // global pooled row
        const uint32_t* rA = Hq + (y0 + g) * HJ;         // dy = g rows
        const uint32_t* r4 = Hq + (y0 + 4) * HJ + g;     // dy = 4 row
        float* orow = outb + oy * OUT_DIM + 2 * g;

        #pragma unroll
        for (int sub = 0; sub < 14; ++sub) {
            const int j0 = sub * 8;
            f32x4 accA = {0.f, 0.f, 0.f, 0.f};
            f32x4 accB = {0.f, 0.f, 0.f, 0.f};

            u32x4 a1 = { rA[j0], rA[j0 + 1], rA[j0 + 2], r4[j0] };
            accA = __builtin_amdgcn_mfma_f32_16x16x32_f16(
                       __builtin_bit_cast(h8t, a1), B1, accA, 0, 0, 0);
            u32x4 c1 = { rA[j0 + HJ], rA[j0 + 1 + HJ], rA[j0 + 2 + HJ], r4[j0 + HJ] };
            accB = __builtin_amdgcn_mfma_f32_16x16x32_f16(
                       __builtin_bit_cast(h8t, c1), B1, accB, 0, 0, 0);

            // maxpool (commutes with monotone BN scale>0 + ReLU) then epilogue
            float m0 = fmaxf(fmaxf(accA[0], accA[1]), fmaxf(accB[0], accB[1]));
            float m1 = fmaxf(fmaxf(accA[2], accA[3]), fmaxf(accB[2], accB[3]));
            float y0v = fmaxf(fmaf(m0, sc, sh), 0.f);
            float y1v = fmaxf(fmaf(m1, sc, sh), 0.f);
            *(float2*)(orow + sub * 8) = make_float2(y0v, y1v);
        }
    }
}

extern "C" void kernel_launch(void* const* d_in, const int* in_sizes, int n_in,
                              void* d_out, int out_size, void* d_ws, size_t ws_size,
                              hipStream_t stream) {
    const float* x        = (const float*)d_in[0];
    const float* conv_w   = (const float*)d_in[1];
    const float* conv_b   = (const float*)d_in[2];
    const float* gamma    = (const float*)d_in[3];
    const float* beta     = (const float*)d_in[4];
    const float* run_mean = (const float*)d_in[5];
    const float* run_var  = (const float*)d_in[6];
    float* out = (float*)d_out;

    dim3 grid(IMG / TILE_Y, 128);   // 7 strips x 128 batch
    dim3 block(256);
    conv_bn_relu_pool<<<grid, block, 0, stream>>>(
        x, conv_w, conv_b, gamma, beta, run_mean, run_var, out);
}